// Round 4
// baseline (462.207 us; speedup 1.0000x reference)
//
#include <hip/hip_runtime.h>
#include <math.h>

// Problem constants
#define NB    8
#define CIMG  64
#define HH    256
#define WW    256
#define NL    68
#define NP    136          // 2*NL
#define JD    128          // hidden dim
#define NSYS  71           // 68 + 3 rows
#define NCOL  73           // 71 matrix cols + 2 rhs
#define CPAD  74           // column stride in doubles (even -> every column 16B aligned)
#define NCHK  32           // K1 split-K chunks
#define CHUNK4 1536        // float4 per chunk (6144 floats)
#define ROW4  49152        // float4 per K-row (196608/4)

// d_out (f32) layout: warped [0, 33554432), pred [33554432, +1088), norm at 33555520
#define OUT_PRED 33554432
#define OUT_NORM 33555520

// d_ws (float) layout
#define WS_PART 0          // 32*128*8 = 32768 floats
#define WS_NORM 32768      // 8 floats (per-batch sum of disp^2)
#define WS_DST  32784      // 8*136 floats (control points, y/x interleaved)
#define WS_WV   33920      // 8*142 floats (w[68][2] then v[3][2] per batch)

// ---------------------------------------------------------------- K1: h partials
__global__ __launch_bounds__(256) void k1_gemv(const float* __restrict__ x,
                                               const float* __restrict__ W1,
                                               float* __restrict__ part) {
  const int jg  = blockIdx.x;   // 0..31 : group of 4 output rows
  const int ch  = blockIdx.y;   // 0..31 : K chunk
  const int tid = threadIdx.x;
  const float4* __restrict__ xv = (const float4*)x;
  const float4* __restrict__ wv = (const float4*)W1;

  float acc[4][8];
#pragma unroll
  for (int a = 0; a < 4; ++a)
#pragma unroll
    for (int b = 0; b < 8; ++b) acc[a][b] = 0.f;

  const int base = ch * CHUNK4;
#pragma unroll
  for (int it = 0; it < 6; ++it) {
    const int k4 = base + it * 256 + tid;
    float4 w[4];
#pragma unroll
    for (int jj = 0; jj < 4; ++jj)
      w[jj] = wv[(size_t)(jg * 4 + jj) * ROW4 + k4];
#pragma unroll
    for (int b = 0; b < 8; ++b) {
      const float4 xr = xv[(size_t)b * ROW4 + k4];
#pragma unroll
      for (int jj = 0; jj < 4; ++jj) {
        acc[jj][b] = fmaf(w[jj].x, xr.x, acc[jj][b]);
        acc[jj][b] = fmaf(w[jj].y, xr.y, acc[jj][b]);
        acc[jj][b] = fmaf(w[jj].z, xr.z, acc[jj][b]);
        acc[jj][b] = fmaf(w[jj].w, xr.w, acc[jj][b]);
      }
    }
  }
  // wave64 reduction
#pragma unroll
  for (int jj = 0; jj < 4; ++jj)
#pragma unroll
    for (int b = 0; b < 8; ++b) {
      float v = acc[jj][b];
      for (int o = 32; o > 0; o >>= 1) v += __shfl_down(v, o, 64);
      acc[jj][b] = v;
    }
  __shared__ float sred[4][32];
  const int lane = tid & 63, wid = tid >> 6;
  if (lane == 0) {
#pragma unroll
    for (int jj = 0; jj < 4; ++jj)
#pragma unroll
      for (int b = 0; b < 8; ++b) sred[wid][jj * 8 + b] = acc[jj][b];
  }
  __syncthreads();
  if (tid < 32) {
    const float s = sred[0][tid] + sred[1][tid] + sred[2][tid] + sred[3][tid];
    const int jj = tid >> 3, b = tid & 7;
    part[((size_t)ch * JD + jg * 4 + jj) * 8 + b] = s;
  }
}

// ------------------- K2: landmarks + f64 TPS solve, ONE WAVE per batch
// Column-major M[c][r] (column stride CPAD=74 doubles -> 16B-aligned columns).
// Lane c owns columns c and c+64. Pivot-column reads are wave-broadcast (free).
__global__ __launch_bounds__(64) void k2_land_solve(
    const float* __restrict__ part, const float* __restrict__ scales,
    const float* __restrict__ lmean, const float* __restrict__ b1,
    const float* __restrict__ W2, const float* __restrict__ b2,
    const float* __restrict__ W3, const float* __restrict__ b3,
    float* __restrict__ out, float* __restrict__ ws) {
  const int b = blockIdx.x, lane = threadIdx.x;
  __shared__ float s_h[JD];
  __shared__ float s_dst[NP];
  __shared__ float s_disp[NP];
  __shared__ double M[NCOL][CPAD];   // M[c][r]

  // h[b][j] = b1[j] + sum_chunks part
  for (int j = lane; j < JD; j += 64) {
    float s = b1[j];
#pragma unroll 8
    for (int c = 0; c < NCHK; ++c) s += part[((size_t)c * JD + j) * 8 + b];
    s_h[j] = s;
  }
  __syncthreads();

  // pred / disp
  const float scale_b = scales[b];
  for (int i = lane; i < NP; i += 64) {
    const float4* w2 = (const float4*)(W2 + (size_t)i * JD);
    const float4* w3 = (const float4*)(W3 + (size_t)i * JD);
    float a2 = 0.f, a3 = 0.f;
#pragma unroll 8
    for (int k = 0; k < 32; ++k) {
      const float4 u = w2[k], v = w3[k];
      const float h0 = s_h[4 * k], h1 = s_h[4 * k + 1];
      const float h2 = s_h[4 * k + 2], h3 = s_h[4 * k + 3];
      a2 = fmaf(u.x, h0, fmaf(u.y, h1, fmaf(u.z, h2, fmaf(u.w, h3, a2))));
      a3 = fmaf(v.x, h0, fmaf(v.y, h1, fmaf(v.z, h2, fmaf(v.w, h3, a3))));
    }
    const float pred = a2 + b2[i] + lmean[i];
    const float disp = (a3 + b3[i]) * scale_b;
    out[OUT_PRED + b * NP + i] = pred;
    s_dst[i]  = pred + disp;   // train points (dst)
    s_disp[i] = disp;          // flows (dst - src)
  }
  __syncthreads();

  // per-batch sum of squared disp + export dst control points
  {
    float s = 0.f;
    for (int i = lane; i < NP; i += 64) {
      const float d = s_disp[i];
      s = fmaf(d, d, s);
      ws[WS_DST + b * NP + i] = s_dst[i];
    }
    for (int o = 32; o > 0; o >>= 1) s += __shfl_down(s, o, 64);
    if (lane == 0) ws[WS_NORM + b] = s;
  }

  // build augmented system, column-major, f64 entries from f32 points
  for (int e = lane; e < NCOL * NSYS; e += 64) {
    const int c = e / NSYS, r = e - c * NSYS;
    double val;
    if (c < NL) {
      if (r < NL) {
        const double dy = (double)s_dst[2 * r]     - (double)s_dst[2 * c];
        const double dx = (double)s_dst[2 * r + 1] - (double)s_dst[2 * c + 1];
        const double d2 = dy * dy + dx * dx;
        val = 0.5 * d2 * log(fmax(d2, 1e-10));
        if (r == c) val += 1e-6;
      } else {
        const int q = r - NL;
        val = (q == 0) ? (double)s_dst[2 * c] : (q == 1) ? (double)s_dst[2 * c + 1] : 1.0;
      }
    } else if (c < NSYS) {       // B columns: y, x, 1 (zero in bottom-right block)
      val = (r < NL) ? ((c == NL) ? (double)s_dst[2 * r]
                        : (c == NL + 1) ? (double)s_dst[2 * r + 1] : 1.0)
                     : 0.0;
    } else {                     // rhs columns 71,72
      val = (r < NL) ? (double)s_disp[2 * r + (c - NSYS)] : 0.0;
    }
    M[c][r] = val;
  }
  __syncthreads();

  // GE with partial pivoting, physical row swaps, wave-synchronous
  for (int p = 0; p < NSYS; ++p) {
    // argmax |M[p][r]| over r in [p, NSYS)  (first-max tie-break like idamax)
    double av = -1.0; int ar = 127;
    const int r1 = p + lane;
    if (r1 < NSYS) { av = fabs(M[p][r1]); ar = r1; }
    const int r2 = r1 + 64;
    if (r2 < NSYS) { const double a2 = fabs(M[p][r2]); if (a2 > av) { av = a2; ar = r2; } }
#pragma unroll
    for (int o = 1; o < 64; o <<= 1) {
      const double ov = __shfl_xor(av, o);
      const int   orr = __shfl_xor(ar, o);
      if (ov > av || (ov == av && orr < ar)) { av = ov; ar = orr; }
    }
    const int piv = ar;
    if (piv != p) {
      for (int c = lane; c < NCOL; c += 64) {
        const double t = M[c][p]; M[c][p] = M[c][piv]; M[c][piv] = t;
      }
    }
    __syncthreads();
    const double inv = 1.0 / M[p][p];
    for (int c = lane; c < NCOL; c += 64) {
      if (c <= p) continue;
      const double cp = M[c][p];
      int r = p + 1;
      if (r & 1) {
        const double f = M[p][r] * inv;
        M[c][r] = fma(-f, cp, M[c][r]);
        ++r;
      }
      for (; r + 1 < NSYS; r += 2) {
        const double2 mp = *(const double2*)&M[p][r];   // broadcast (same addr all lanes)
        double2 mc = *(double2*)&M[c][r];
        mc.x = fma(-(mp.x * inv), cp, mc.x);
        mc.y = fma(-(mp.y * inv), cp, mc.y);
        *(double2*)&M[c][r] = mc;
      }
      if (r < NSYS) {
        const double f = M[p][r] * inv;
        M[c][r] = fma(-f, cp, M[c][r]);
      }
    }
    __syncthreads();
  }

  // back substitution (2 rhs). Lane owns row 'lane' (a) and row 'lane+64' (b, lanes 0..6).
  const int rA = lane, rB = lane + 64;
  const bool hasB = (rB < NSYS);
  double bb0a = M[NSYS][rA],     bb1a = M[NSYS + 1][rA],     diagA = M[rA][rA];
  double bb0b = 0.0, bb1b = 0.0, diagB = 1.0;
  if (hasB) { bb0b = M[NSYS][rB]; bb1b = M[NSYS + 1][rB]; diagB = M[rB][rB]; }
  double acc0a = 0.0, acc1a = 0.0, acc0b = 0.0, acc1b = 0.0;
  double sol0a = 0.0, sol1a = 0.0, sol0b = 0.0, sol1b = 0.0;
  for (int p = NSYS - 1; p >= 0; --p) {
    const double tA0 = (bb0a - acc0a) / diagA;
    const double tA1 = (bb1a - acc1a) / diagA;
    const double tB0 = (bb0b - acc0b) / diagB;
    const double tB1 = (bb1b - acc1b) / diagB;
    const bool fromB = (p >= 64);
    const int  src   = fromB ? (p - 64) : p;
    const double x0 = __shfl(fromB ? tB0 : tA0, src);
    const double x1 = __shfl(fromB ? tB1 : tA1, src);
    if (p >= 64) { if (lane == p - 64) { sol0b = tB0; sol1b = tB1; } }
    else         { if (lane == p)      { sol0a = tA0; sol1a = tA1; } }
    if (rA < p) {
      const double u = M[p][rA];
      acc0a = fma(u, x0, acc0a);
      acc1a = fma(u, x1, acc1a);
    }
    if (hasB && rB < p) {
      const double u = M[p][rB];
      acc0b = fma(u, x0, acc0b);
      acc1b = fma(u, x1, acc1b);
    }
  }
  ws[WS_WV + (size_t)b * 142 + 2 * rA]     = (float)sol0a;
  ws[WS_WV + (size_t)b * 142 + 2 * rA + 1] = (float)sol1a;
  if (hasB) {
    ws[WS_WV + (size_t)b * 142 + 2 * rB]     = (float)sol0b;
    ws[WS_WV + (size_t)b * 142 + 2 * rB + 1] = (float)sol1b;
  }
}

// ------------------------------- K3: fused spline eval + bilinear warp (+norm finalize)
// XCD swizzle: batch image b -> XCD b, so consecutive y rows share that XCD's L2.
__global__ __launch_bounds__(256) void k3_warp(const float* __restrict__ img,
                                               const float* __restrict__ ws,
                                               float* __restrict__ out) {
  const int orig = blockIdx.x;
  const int wgid = (orig & 7) * 256 + (orig >> 3);   // bijective (2048 % 8 == 0)
  const int b = wgid >> 8, y = wgid & 255;
  const int tid = threadIdx.x;   // = x

  if (orig == 0 && tid == 0) {
    float s = 0.f;
    for (int i = 0; i < NB; ++i) s += sqrtf(ws[WS_NORM + i]);
    out[OUT_NORM] = s * 0.125f;
  }

  __shared__ float s_c[NP], s_w[NP], s_v[6];
  if (tid < NP) {
    s_c[tid] = ws[WS_DST + b * NP + tid];
    s_w[tid] = ws[WS_WV + (size_t)b * 142 + tid];
  }
  if (tid >= NP && tid < NP + 6) s_v[tid - NP] = ws[WS_WV + (size_t)b * 142 + tid];
  __syncthreads();

  const float yf = (float)y, xf = (float)tid;
  float fy = fmaf(s_v[0], yf, fmaf(s_v[2], xf, s_v[4]));
  float fx = fmaf(s_v[1], yf, fmaf(s_v[3], xf, s_v[5]));
#pragma unroll 4
  for (int l = 0; l < NL; ++l) {
    const float dy = yf - s_c[2 * l];
    const float dx = xf - s_c[2 * l + 1];
    const float r  = fmaf(dy, dy, dx * dx);
    const float ph = 0.5f * r * __logf(fmaxf(r, 1e-10f));
    fy = fmaf(s_w[2 * l],     ph, fy);
    fx = fmaf(s_w[2 * l + 1], ph, fx);
  }

  const float qy = fminf(fmaxf(yf - fy, 0.f), 255.f);
  const float qx = fminf(fmaxf(xf - fx, 0.f), 255.f);
  int y0 = (int)floorf(qy); y0 = y0 > 254 ? 254 : y0;
  int x0 = (int)floorf(qx); x0 = x0 > 254 ? 254 : x0;
  const float wy = qy - (float)y0, wx = qx - (float)x0;
  const float w00 = (1.f - wy) * (1.f - wx), w01 = (1.f - wy) * wx;
  const float w10 = wy * (1.f - wx),         w11 = wy * wx;

  const float* p0 = img + (size_t)b * CIMG * 65536 + y0 * 256 + x0;
  const size_t ob = (size_t)b * CIMG * 65536 + (size_t)y * 256 + tid;
#pragma unroll 4
  for (int c = 0; c < CIMG; ++c) {
    const float* p = p0 + (size_t)c * 65536;
    const float v00 = p[0], v01 = p[1], v10 = p[256], v11 = p[257];
    const float val = fmaf(w00, v00, fmaf(w01, v01, fmaf(w10, v10, w11 * v11)));
    out[ob + (size_t)c * 65536] = val;
  }
}

// ------------------------------------------------------------------ launcher
extern "C" void kernel_launch(void* const* d_in, const int* in_sizes, int n_in,
                              void* d_out, int out_size, void* d_ws, size_t ws_size,
                              hipStream_t stream) {
  const float* x      = (const float*)d_in[0];
  const float* img    = (const float*)d_in[1];
  const float* scales = (const float*)d_in[2];
  const float* lmean  = (const float*)d_in[3];
  const float* W1     = (const float*)d_in[4];
  const float* b1     = (const float*)d_in[5];
  const float* W2     = (const float*)d_in[6];
  const float* b2     = (const float*)d_in[7];
  const float* W3     = (const float*)d_in[8];
  const float* b3     = (const float*)d_in[9];
  float* out = (float*)d_out;
  float* ws  = (float*)d_ws;

  k1_gemv<<<dim3(32, 32), 256, 0, stream>>>(x, W1, ws + WS_PART);
  k2_land_solve<<<NB, 64, 0, stream>>>(ws + WS_PART, scales, lmean, b1, W2, b2, W3, b3, out, ws);
  k3_warp<<<NB * HH, 256, 0, stream>>>(img, ws, out);
}

// Round 5
// 327.863 us; speedup vs baseline: 1.4098x; 1.4098x over previous
//
#include <hip/hip_runtime.h>
#include <math.h>

// Problem constants
#define NB    8
#define CIMG  64
#define HH    256
#define WW    256
#define NL    68
#define NP    136          // 2*NL
#define JD    128          // hidden dim
#define NSYS  71           // 68 + 3 rows
#define NCOL  73           // 71 matrix cols + 2 rhs
#define NCHK  32           // K1 split-K chunks
#define CHUNK4 1536        // float4 per chunk (6144 floats)
#define ROW4  49152        // float4 per K-row (196608/4)
#define CH    10           // static-unroll chunk width over columns

// d_out (f32) layout: warped [0, 33554432), pred [33554432, +1088), norm at 33555520
#define OUT_PRED 33554432
#define OUT_NORM 33555520

// d_ws (float) layout
#define WS_PART 0          // 32*128*8 = 32768 floats
#define WS_NORM 32768      // 8 floats (per-batch sum of disp^2)
#define WS_DST  32784      // 8*136 floats (control points, y/x interleaved)
#define WS_WV   33920      // 8*142 floats (w[68][2] then v[3][2] per batch)

// readlane broadcast of an f64 (uniform source lane) — VALU, not LDS
__device__ __forceinline__ double rl_f64(double v, int sl) {
  const int lo = __builtin_amdgcn_readlane(__double2loint(v), sl);
  const int hi = __builtin_amdgcn_readlane(__double2hiint(v), sl);
  return __hiloint2double(hi, lo);
}

// ---------------------------------------------------------------- K1: h partials
__global__ __launch_bounds__(256) void k1_gemv(const float* __restrict__ x,
                                               const float* __restrict__ W1,
                                               float* __restrict__ part) {
  const int jg  = blockIdx.x;   // 0..31 : group of 4 output rows
  const int ch  = blockIdx.y;   // 0..31 : K chunk
  const int tid = threadIdx.x;
  const float4* __restrict__ xv = (const float4*)x;
  const float4* __restrict__ wv = (const float4*)W1;

  float acc[4][8];
#pragma unroll
  for (int a = 0; a < 4; ++a)
#pragma unroll
    for (int b = 0; b < 8; ++b) acc[a][b] = 0.f;

  const int base = ch * CHUNK4;
#pragma unroll
  for (int it = 0; it < 6; ++it) {
    const int k4 = base + it * 256 + tid;
    float4 w[4];
#pragma unroll
    for (int jj = 0; jj < 4; ++jj)
      w[jj] = wv[(size_t)(jg * 4 + jj) * ROW4 + k4];
#pragma unroll
    for (int b = 0; b < 8; ++b) {
      const float4 xr = xv[(size_t)b * ROW4 + k4];
#pragma unroll
      for (int jj = 0; jj < 4; ++jj) {
        acc[jj][b] = fmaf(w[jj].x, xr.x, acc[jj][b]);
        acc[jj][b] = fmaf(w[jj].y, xr.y, acc[jj][b]);
        acc[jj][b] = fmaf(w[jj].z, xr.z, acc[jj][b]);
        acc[jj][b] = fmaf(w[jj].w, xr.w, acc[jj][b]);
      }
    }
  }
  // wave64 reduction
#pragma unroll
  for (int jj = 0; jj < 4; ++jj)
#pragma unroll
    for (int b = 0; b < 8; ++b) {
      float v = acc[jj][b];
      for (int o = 32; o > 0; o >>= 1) v += __shfl_down(v, o, 64);
      acc[jj][b] = v;
    }
  __shared__ float sred[4][32];
  const int lane = tid & 63, wid = tid >> 6;
  if (lane == 0) {
#pragma unroll
    for (int jj = 0; jj < 4; ++jj)
#pragma unroll
      for (int b = 0; b < 8; ++b) sred[wid][jj * 8 + b] = acc[jj][b];
  }
  __syncthreads();
  if (tid < 32) {
    const float s = sred[0][tid] + sred[1][tid] + sred[2][tid] + sred[3][tid];
    const int jj = tid >> 3, b = tid & 7;
    part[((size_t)ch * JD + jg * 4 + jj) * 8 + b] = s;
  }
}

// ------------------- K2: landmarks + f64 TPS solve, ONE WAVE per batch,
// entire system in REGISTERS (lane = row; lanes 0..6 own a second row).
// Inner loop: v_readlane broadcasts + f64 fma only — no LDS on the critical path.
__global__ __launch_bounds__(64, 1) void k2_land_solve(
    const float* __restrict__ part, const float* __restrict__ scales,
    const float* __restrict__ lmean, const float* __restrict__ b1,
    const float* __restrict__ W2, const float* __restrict__ b2,
    const float* __restrict__ W3, const float* __restrict__ b3,
    float* __restrict__ out, float* __restrict__ ws) {
  const int b = blockIdx.x, lane = threadIdx.x;
  __shared__ float  s_h[JD];
  __shared__ float  s_dst[NP];
  __shared__ float  s_disp[NP];
  __shared__ double Mb[NCOL][72];   // [col][pivot-slot] triangular dump for back-sub

  // ---- h[b][j] = b1[j] + sum_chunks part
  for (int j = lane; j < JD; j += 64) {
    float s = b1[j];
#pragma unroll 8
    for (int c = 0; c < NCHK; ++c) s += part[((size_t)c * JD + j) * 8 + b];
    s_h[j] = s;
  }
  __syncthreads();

  // ---- pred / disp
  const float scale_b = scales[b];
  for (int i = lane; i < NP; i += 64) {
    const float4* w2 = (const float4*)(W2 + (size_t)i * JD);
    const float4* w3 = (const float4*)(W3 + (size_t)i * JD);
    float a2 = 0.f, a3 = 0.f;
#pragma unroll 8
    for (int k = 0; k < 32; ++k) {
      const float4 u = w2[k], v = w3[k];
      const float h0 = s_h[4 * k], h1 = s_h[4 * k + 1];
      const float h2 = s_h[4 * k + 2], h3 = s_h[4 * k + 3];
      a2 = fmaf(u.x, h0, fmaf(u.y, h1, fmaf(u.z, h2, fmaf(u.w, h3, a2))));
      a3 = fmaf(v.x, h0, fmaf(v.y, h1, fmaf(v.z, h2, fmaf(v.w, h3, a3))));
    }
    const float pred = a2 + b2[i] + lmean[i];
    const float disp = (a3 + b3[i]) * scale_b;
    out[OUT_PRED + b * NP + i] = pred;
    s_dst[i]  = pred + disp;
    s_disp[i] = disp;
  }
  __syncthreads();

  // ---- norm partial + export control points
  {
    float s = 0.f;
    for (int i = lane; i < NP; i += 64) {
      const float d = s_disp[i];
      s = fmaf(d, d, s);
      ws[WS_DST + b * NP + i] = s_dst[i];
    }
    for (int o = 32; o > 0; o >>= 1) s += __shfl_down(s, o, 64);
    if (lane == 0) ws[WS_NORM + b] = s;
  }

  // ---- build rows into registers (f64)
  const int rA = lane, rB = lane + 64;
  const bool hasB = (rB < NSYS);
  double A_[NCOL], B_[NCOL];
  {
    const double ay = (double)s_dst[2 * rA], ax = (double)s_dst[2 * rA + 1];
#pragma unroll
    for (int c = 0; c < NL; ++c) {
      const double dy = ay - (double)s_dst[2 * c];
      const double dx = ax - (double)s_dst[2 * c + 1];
      const double d2 = dy * dy + dx * dx;
      double v = 0.5 * d2 * log(fmax(d2, 1e-10));
      if (c == rA) v += 1e-6;
      A_[c] = v;
    }
    A_[68] = ay; A_[69] = ax; A_[70] = 1.0;
    A_[71] = (double)s_disp[2 * rA];
    A_[72] = (double)s_disp[2 * rA + 1];
  }
  if (hasB) {
    if (rB < NL) {
      const double by = (double)s_dst[2 * rB], bx = (double)s_dst[2 * rB + 1];
#pragma unroll
      for (int c = 0; c < NL; ++c) {
        const double dy = by - (double)s_dst[2 * c];
        const double dx = bx - (double)s_dst[2 * c + 1];
        const double d2 = dy * dy + dx * dx;
        double v = 0.5 * d2 * log(fmax(d2, 1e-10));
        if (c == rB) v += 1e-6;
        B_[c] = v;
      }
      B_[68] = by; B_[69] = bx; B_[70] = 1.0;
      B_[71] = (double)s_disp[2 * rB];
      B_[72] = (double)s_disp[2 * rB + 1];
    } else {
      const int q = rB - NL;   // 0,1,2 -> y, x, 1 rows of B^T
#pragma unroll
      for (int c = 0; c < NL; ++c)
        B_[c] = (q == 0) ? (double)s_dst[2 * c] : (q == 1) ? (double)s_dst[2 * c + 1] : 1.0;
#pragma unroll
      for (int c = NL; c < NCOL; ++c) B_[c] = 0.0;
    }
  } else {
#pragma unroll
    for (int c = 0; c < NCOL; ++c) B_[c] = 0.0;
  }

  // ---- Gaussian elimination, no-swap partial pivoting, wave-synchronous
  double cvA = A_[0], cvB = B_[0];    // current column-p value per owned row
  bool actA = true, actB = hasB;
  int slotA = 0, slotB = 0;

#pragma unroll 1
  for (int p = 0; p < NSYS; ++p) {
    // packed argmax: f32 magnitude prefix | row index (7 bits)
    unsigned ua = actA ? ((__float_as_uint((float)fabs(cvA)) & 0xFFFFFF80u) | (unsigned)rA) : 0u;
    unsigned ub = actB ? ((__float_as_uint((float)fabs(cvB)) & 0xFFFFFF80u) | (unsigned)rB) : 0u;
    unsigned u = ua > ub ? ua : ub;
#pragma unroll
    for (int o = 1; o < 64; o <<= 1) {
      const unsigned v = __shfl_xor(u, o);
      if (v > u) u = v;
    }
    const int piv = __builtin_amdgcn_readfirstlane((int)(u & 0x7Fu));
    const int pidx = (piv < 64) ? piv : (piv - 64);
    const double pvA = rl_f64(cvA, pidx);
    const double pvB = rl_f64(cvB, pidx);
    const double inv = 1.0 / ((piv < 64) ? pvA : pvB);

    if (rA == piv) { actA = false; slotA = p; }
    if (actB && rB == piv) { actB = false; slotB = p; }
    const double mA = actA ? cvA * inv : 0.0;   // frozen rows: m=0 -> exact no-op fma
    const double mB = actB ? cvB * inv : 0.0;

    if (piv < 64) {
#pragma unroll
      for (int ch = 0; ch < 8; ++ch) {
        if (ch * CH + CH > p) {                  // skip chunks entirely below pivot col
#pragma unroll
          for (int cc = 0; cc < CH; ++cc) {
            const int c = ch * CH + cc;
            if (c < NCOL) {
              const double pr = rl_f64(A_[c], piv);
              A_[c] = fma(-mA, pr, A_[c]);
              B_[c] = fma(-mB, pr, B_[c]);
            }
          }
        }
      }
    } else {
      const int pl = piv - 64;
#pragma unroll
      for (int ch = 0; ch < 8; ++ch) {
        if (ch * CH + CH > p) {
#pragma unroll
          for (int cc = 0; cc < CH; ++cc) {
            const int c = ch * CH + cc;
            if (c < NCOL) {
              const double pr = rl_f64(B_[c], pl);
              A_[c] = fma(-mA, pr, A_[c]);
              B_[c] = fma(-mB, pr, B_[c]);
            }
          }
        }
      }
    }

    // extract next pivot-column value (static-index scan of one chunk)
    const int pn = p + 1;
#pragma unroll
    for (int ch = 0; ch < 8; ++ch) {
      if (pn >= ch * CH && pn < ch * CH + CH) {
#pragma unroll
        for (int cc = 0; cc < CH; ++cc) {
          const int c = ch * CH + cc;
          if (c < NCOL && c == pn) { cvA = A_[c]; cvB = B_[c]; }
        }
      }
    }
  }

  // ---- dump triangular system to LDS in pivot-slot order: Mb[col][slot]
#pragma unroll
  for (int c = 0; c < NCOL; ++c) Mb[c][slotA] = A_[c];
  if (hasB) {
#pragma unroll
    for (int c = 0; c < NCOL; ++c) Mb[c][slotB] = B_[c];
  }
  __syncthreads();

  // ---- back substitution (2 rhs); lane solves variable 'lane' (+ lane+64)
  const double bb0a = Mb[NSYS][rA], bb1a = Mb[NSYS + 1][rA];
  const double diA = 1.0 / Mb[rA][rA];
  double bb0b = 0.0, bb1b = 0.0, diB = 0.0;
  if (hasB) { bb0b = Mb[NSYS][rB]; bb1b = Mb[NSYS + 1][rB]; diB = 1.0 / Mb[rB][rB]; }
  double acc0a = 0.0, acc1a = 0.0, acc0b = 0.0, acc1b = 0.0;
  double sol0a = 0.0, sol1a = 0.0, sol0b = 0.0, sol1b = 0.0;
#pragma unroll 1
  for (int p = NSYS - 1; p >= 0; --p) {
    const double tA0 = (bb0a - acc0a) * diA;
    const double tA1 = (bb1a - acc1a) * diA;
    const double tB0 = (bb0b - acc0b) * diB;
    const double tB1 = (bb1b - acc1b) * diB;
    const bool fromB = (p >= 64);
    const int  src   = fromB ? (p - 64) : p;
    const double x0 = rl_f64(fromB ? tB0 : tA0, src);
    const double x1 = rl_f64(fromB ? tB1 : tA1, src);
    if (p >= 64) { if (lane == p - 64) { sol0b = tB0; sol1b = tB1; } }
    else         { if (lane == p)      { sol0a = tA0; sol1a = tA1; } }
    if (rA < p) {
      const double u2 = Mb[p][rA];
      acc0a = fma(u2, x0, acc0a);
      acc1a = fma(u2, x1, acc1a);
    }
    if (hasB && rB < p) {
      const double u2 = Mb[p][rB];
      acc0b = fma(u2, x0, acc0b);
      acc1b = fma(u2, x1, acc1b);
    }
  }
  ws[WS_WV + (size_t)b * 142 + 2 * rA]     = (float)sol0a;
  ws[WS_WV + (size_t)b * 142 + 2 * rA + 1] = (float)sol1a;
  if (hasB) {
    ws[WS_WV + (size_t)b * 142 + 2 * rB]     = (float)sol0b;
    ws[WS_WV + (size_t)b * 142 + 2 * rB + 1] = (float)sol1b;
  }
}

// ------------------------------- K3: fused spline eval + bilinear warp (+norm finalize)
__global__ __launch_bounds__(256) void k3_warp(const float* __restrict__ img,
                                               const float* __restrict__ ws,
                                               float* __restrict__ out) {
  const int orig = blockIdx.x;
  const int wgid = (orig & 7) * 256 + (orig >> 3);   // bijective (2048 % 8 == 0)
  const int b = wgid >> 8, y = wgid & 255;
  const int tid = threadIdx.x;   // = x

  if (orig == 0 && tid == 0) {
    float s = 0.f;
    for (int i = 0; i < NB; ++i) s += sqrtf(ws[WS_NORM + i]);
    out[OUT_NORM] = s * 0.125f;
  }

  __shared__ float s_c[NP], s_w[NP], s_v[6];
  if (tid < NP) {
    s_c[tid] = ws[WS_DST + b * NP + tid];
    s_w[tid] = ws[WS_WV + (size_t)b * 142 + tid];
  }
  if (tid >= NP && tid < NP + 6) s_v[tid - NP] = ws[WS_WV + (size_t)b * 142 + tid];
  __syncthreads();

  const float yf = (float)y, xf = (float)tid;
  float fy = fmaf(s_v[0], yf, fmaf(s_v[2], xf, s_v[4]));
  float fx = fmaf(s_v[1], yf, fmaf(s_v[3], xf, s_v[5]));
#pragma unroll 4
  for (int l = 0; l < NL; ++l) {
    const float dy = yf - s_c[2 * l];
    const float dx = xf - s_c[2 * l + 1];
    const float r  = fmaf(dy, dy, dx * dx);
    const float ph = 0.5f * r * __logf(fmaxf(r, 1e-10f));
    fy = fmaf(s_w[2 * l],     ph, fy);
    fx = fmaf(s_w[2 * l + 1], ph, fx);
  }

  const float qy = fminf(fmaxf(yf - fy, 0.f), 255.f);
  const float qx = fminf(fmaxf(xf - fx, 0.f), 255.f);
  int y0 = (int)floorf(qy); y0 = y0 > 254 ? 254 : y0;
  int x0 = (int)floorf(qx); x0 = x0 > 254 ? 254 : x0;
  const float wy = qy - (float)y0, wx = qx - (float)x0;
  const float w00 = (1.f - wy) * (1.f - wx), w01 = (1.f - wy) * wx;
  const float w10 = wy * (1.f - wx),         w11 = wy * wx;

  const float* p0 = img + (size_t)b * CIMG * 65536 + y0 * 256 + x0;
  const size_t ob = (size_t)b * CIMG * 65536 + (size_t)y * 256 + tid;
#pragma unroll 4
  for (int c = 0; c < CIMG; ++c) {
    const float* p = p0 + (size_t)c * 65536;
    const float v00 = p[0], v01 = p[1], v10 = p[256], v11 = p[257];
    const float val = fmaf(w00, v00, fmaf(w01, v01, fmaf(w10, v10, w11 * v11)));
    __builtin_nontemporal_store(val, &out[ob + (size_t)c * 65536]);
  }
}

// ------------------------------------------------------------------ launcher
extern "C" void kernel_launch(void* const* d_in, const int* in_sizes, int n_in,
                              void* d_out, int out_size, void* d_ws, size_t ws_size,
                              hipStream_t stream) {
  const float* x      = (const float*)d_in[0];
  const float* img    = (const float*)d_in[1];
  const float* scales = (const float*)d_in[2];
  const float* lmean  = (const float*)d_in[3];
  const float* W1     = (const float*)d_in[4];
  const float* b1     = (const float*)d_in[5];
  const float* W2     = (const float*)d_in[6];
  const float* b2     = (const float*)d_in[7];
  const float* W3     = (const float*)d_in[8];
  const float* b3     = (const float*)d_in[9];
  float* out = (float*)d_out;
  float* ws  = (float*)d_ws;

  k1_gemv<<<dim3(32, 32), 256, 0, stream>>>(x, W1, ws + WS_PART);
  k2_land_solve<<<NB, 64, 0, stream>>>(ws + WS_PART, scales, lmean, b1, W2, b2, W3, b3, out, ws);
  k3_warp<<<NB * HH, 256, 0, stream>>>(img, ws, out);
}

// Round 6
// 201.790 us; speedup vs baseline: 2.2905x; 1.6248x over previous
//
#include <hip/hip_runtime.h>
#include <math.h>

// Problem constants
#define NB    8
#define CIMG  64
#define HH    256
#define WW    256
#define NL    68
#define NP    136          // 2*NL
#define JD    128          // hidden dim
#define NSYS  71           // 68 + 3 rows
#define NCOL  73           // 71 matrix cols + 2 rhs
#define SEG   19           // columns per wave (4 waves: 19+19+19+16)
#define NCHK  32           // K1 split-K chunks
#define CHUNK4 1536        // float4 per chunk (6144 floats)
#define ROW4  49152        // float4 per K-row (196608/4)

// d_out (f32) layout: warped [0, 33554432), pred [33554432, +1088), norm at 33555520
#define OUT_PRED 33554432
#define OUT_NORM 33555520

// d_ws (float) layout
#define WS_PART 0          // 32*128*8 = 32768 floats
#define WS_NORM 32768      // 8 floats (per-batch sum of disp^2)
#define WS_DST  32784      // 8*136 floats (control points, y/x interleaved)
#define WS_WV   33920      // 8*142 floats (w[68][2] then v[3][2] per batch)

// readlane broadcast of an f64 (uniform source lane) — VALU, not LDS
__device__ __forceinline__ double rl_f64(double v, int sl) {
  const int lo = __builtin_amdgcn_readlane(__double2loint(v), sl);
  const int hi = __builtin_amdgcn_readlane(__double2hiint(v), sl);
  return __hiloint2double(hi, lo);
}

// ---------------------------------------------------------------- K1: h partials
__global__ __launch_bounds__(256) void k1_gemv(const float* __restrict__ x,
                                               const float* __restrict__ W1,
                                               float* __restrict__ part) {
  const int jg  = blockIdx.x;   // 0..31 : group of 4 output rows
  const int ch  = blockIdx.y;   // 0..31 : K chunk
  const int tid = threadIdx.x;
  const float4* __restrict__ xv = (const float4*)x;
  const float4* __restrict__ wv = (const float4*)W1;

  float acc[4][8];
#pragma unroll
  for (int a = 0; a < 4; ++a)
#pragma unroll
    for (int b = 0; b < 8; ++b) acc[a][b] = 0.f;

  const int base = ch * CHUNK4;
#pragma unroll
  for (int it = 0; it < 6; ++it) {
    const int k4 = base + it * 256 + tid;
    float4 w[4];
#pragma unroll
    for (int jj = 0; jj < 4; ++jj)
      w[jj] = wv[(size_t)(jg * 4 + jj) * ROW4 + k4];
#pragma unroll
    for (int b = 0; b < 8; ++b) {
      const float4 xr = xv[(size_t)b * ROW4 + k4];
#pragma unroll
      for (int jj = 0; jj < 4; ++jj) {
        acc[jj][b] = fmaf(w[jj].x, xr.x, acc[jj][b]);
        acc[jj][b] = fmaf(w[jj].y, xr.y, acc[jj][b]);
        acc[jj][b] = fmaf(w[jj].z, xr.z, acc[jj][b]);
        acc[jj][b] = fmaf(w[jj].w, xr.w, acc[jj][b]);
      }
    }
  }
  // wave64 reduction
#pragma unroll
  for (int jj = 0; jj < 4; ++jj)
#pragma unroll
    for (int b = 0; b < 8; ++b) {
      float v = acc[jj][b];
      for (int o = 32; o > 0; o >>= 1) v += __shfl_down(v, o, 64);
      acc[jj][b] = v;
    }
  __shared__ float sred[4][32];
  const int lane = tid & 63, wid = tid >> 6;
  if (lane == 0) {
#pragma unroll
    for (int jj = 0; jj < 4; ++jj)
#pragma unroll
      for (int b = 0; b < 8; ++b) sred[wid][jj * 8 + b] = acc[jj][b];
  }
  __syncthreads();
  if (tid < 32) {
    const float s = sred[0][tid] + sred[1][tid] + sred[2][tid] + sred[3][tid];
    const int jj = tid >> 3, b = tid & 7;
    part[((size_t)ch * JD + jg * 4 + jj) * 8 + b] = s;
  }
}

// augmented-system entry (f64), matches rounds 2/4/5 numerics
__device__ __forceinline__ double sys_entry(int r, int c,
                                            const float* s_dst,
                                            const float* s_disp) {
  if (r < NL) {
    if (c < NL) {
      const double dy = (double)s_dst[2 * r]     - (double)s_dst[2 * c];
      const double dx = (double)s_dst[2 * r + 1] - (double)s_dst[2 * c + 1];
      const double d2 = dy * dy + dx * dx;
      double v = 0.5 * d2 * log(fmax(d2, 1e-10));
      if (r == c) v += 1e-6;
      return v;
    }
    if (c == 68) return (double)s_dst[2 * r];
    if (c == 69) return (double)s_dst[2 * r + 1];
    if (c == 70) return 1.0;
    return (double)s_disp[2 * r + (c - 71)];   // rhs cols 71,72
  }
  if (c < NL) {
    const int q = r - NL;
    return (q == 0) ? (double)s_dst[2 * c] : (q == 1) ? (double)s_dst[2 * c + 1] : 1.0;
  }
  return 0.0;
}

// ------------------- K2: landmarks + f64 TPS solve (column-sharded, 4 waves/batch)
// Every wave holds ALL 71 rows but only a 19-col shard in registers
// (lane = row; lanes 0..6 also own rows 64..70). Pivot-row broadcast is
// wave-local readlane; pivot-col multipliers cross waves via double-buffered
// LDS -> exactly ONE __syncthreads per elimination step.
__global__ __launch_bounds__(256) void k2_land_solve(
    const float* __restrict__ part, const float* __restrict__ scales,
    const float* __restrict__ lmean, const float* __restrict__ b1,
    const float* __restrict__ W2, const float* __restrict__ b2,
    const float* __restrict__ W3, const float* __restrict__ b3,
    float* __restrict__ out, float* __restrict__ ws) {
  const int b = blockIdx.x, tid = threadIdx.x;
  const int lane = tid & 63, wv = tid >> 6;
  __shared__ float  s_h[JD];
  __shared__ float  s_dst[NP];
  __shared__ float  s_disp[NP];
  __shared__ double Mb[NCOL][72];    // [col][pivot-slot] triangular dump for back-sub
  __shared__ double dmm[2][72];      // double-buffered per-row multipliers
  __shared__ int    s_piv[2];

  // ---- h[b][j] = b1[j] + sum_chunks part
  if (tid < JD) {
    float s = b1[tid];
#pragma unroll 8
    for (int c = 0; c < NCHK; ++c) s += part[((size_t)c * JD + tid) * 8 + b];
    s_h[tid] = s;
  }
  __syncthreads();

  // ---- pred / disp
  const float scale_b = scales[b];
  if (tid < NP) {
    const float4* w2 = (const float4*)(W2 + (size_t)tid * JD);
    const float4* w3 = (const float4*)(W3 + (size_t)tid * JD);
    float a2 = 0.f, a3 = 0.f;
#pragma unroll 8
    for (int k = 0; k < 32; ++k) {
      const float4 u = w2[k], v = w3[k];
      const float h0 = s_h[4 * k], h1 = s_h[4 * k + 1];
      const float h2 = s_h[4 * k + 2], h3 = s_h[4 * k + 3];
      a2 = fmaf(u.x, h0, fmaf(u.y, h1, fmaf(u.z, h2, fmaf(u.w, h3, a2))));
      a3 = fmaf(v.x, h0, fmaf(v.y, h1, fmaf(v.z, h2, fmaf(v.w, h3, a3))));
    }
    const float pred = a2 + b2[tid] + lmean[tid];
    const float disp = (a3 + b3[tid]) * scale_b;
    out[OUT_PRED + b * NP + tid] = pred;
    s_dst[tid]  = pred + disp;
    s_disp[tid] = disp;
  }
  __syncthreads();

  // ---- norm partial + export control points
  if (tid < 64) {
    float s = 0.f;
    for (int i = tid; i < NP; i += 64) { const float d = s_disp[i]; s = fmaf(d, d, s); }
    for (int o = 32; o > 0; o >>= 1) s += __shfl_down(s, o, 64);
    if (tid == 0) ws[WS_NORM + b] = s;
  }
  if (tid < NP) ws[WS_DST + b * NP + tid] = s_dst[tid];

  // ---- build this wave's column shard into registers
  const int rowA = lane, rowB = lane + 64;
  const bool hasB = (rowB < NSYS);
  const int cbase = wv * SEG;
  double seg[SEG], S2[SEG];
#pragma unroll
  for (int i = 0; i < SEG; ++i) {
    const int c = cbase + i;
    double vA = 0.0, vB = 0.0;
    if (c < NCOL) {
      vA = sys_entry(rowA, c, s_dst, s_disp);
      if (hasB) vB = sys_entry(rowB, c, s_dst, s_disp);
    }
    seg[i] = vA; S2[i] = vB;
  }

  // ---- Gaussian elimination, no-swap partial pivoting, 1 barrier/step
  double cvA = seg[0], cvB = S2[0];   // shadow of current pivot column (owner wave)
  bool actA = true, actB = hasB;
  int slotA = 0, slotB = 0;

#pragma unroll 1
  for (int p = 0; p < NSYS; ++p) {
    const int buf = p & 1;
    if (wv == p / SEG) {
      // packed argmax: f32 magnitude prefix | row index (7 bits) — same as r5
      unsigned ua = actA ? ((__float_as_uint((float)fabs(cvA)) & 0xFFFFFF80u) | (unsigned)rowA) : 0u;
      unsigned ub = actB ? ((__float_as_uint((float)fabs(cvB)) & 0xFFFFFF80u) | (unsigned)rowB) : 0u;
      unsigned u = ua > ub ? ua : ub;
#pragma unroll
      for (int o = 1; o < 64; o <<= 1) {
        const unsigned v = __shfl_xor(u, o);
        if (v > u) u = v;
      }
      const int piv = (int)(u & 0x7Fu);
      const double pv = (piv < 64) ? rl_f64(cvA, piv) : rl_f64(cvB, piv - 64);
      const double inv = 1.0 / pv;
      const double mA = (actA && rowA != piv) ? cvA * inv : 0.0;
      const double mB = (actB && rowB != piv) ? cvB * inv : 0.0;
      dmm[buf][lane] = mA;
      if (lane < 7) dmm[buf][64 + lane] = mB;
      if (lane == 0) s_piv[buf] = piv;
    }
    __syncthreads();
    const int piv = __builtin_amdgcn_readfirstlane(s_piv[buf]);
    const double myMA = dmm[buf][lane];
    const double myMB = (lane < 7) ? dmm[buf][64 + lane] : 0.0;
    if (piv == rowA) { actA = false; slotA = p; }
    if (hasB && piv == rowB) { actB = false; slotB = p; }
    const int  pl = (piv < 64) ? piv : piv - 64;
    const bool pB = piv >= 64;
#pragma unroll
    for (int i = 0; i < SEG; ++i) {
      const double pr = pB ? rl_f64(S2[i], pl) : rl_f64(seg[i], pl);
      seg[i] = fma(-myMA, pr, seg[i]);
      S2[i]  = fma(-myMB, pr, S2[i]);
    }
    const int pn = p + 1;
#pragma unroll
    for (int i = 0; i < SEG; ++i) {
      if (cbase + i == pn) { cvA = seg[i]; cvB = S2[i]; }
    }
  }

  // ---- dump triangular system to LDS: Mb[col][slot]
#pragma unroll
  for (int i = 0; i < SEG; ++i) {
    const int c = cbase + i;
    if (c < NCOL) {
      Mb[c][slotA] = seg[i];
      if (hasB) Mb[c][slotB] = S2[i];
    }
  }
  __syncthreads();

  // ---- back substitution (2 rhs) by wave 0; lane solves var 'lane' (+ lane+64)
  if (wv == 0) {
    const int rA = lane, rB = lane + 64;
    const bool hB = (rB < NSYS);
    const double bb0a = Mb[NSYS][rA], bb1a = Mb[NSYS + 1][rA];
    const double diA = 1.0 / Mb[rA][rA];
    double bb0b = 0.0, bb1b = 0.0, diB = 0.0;
    if (hB) { bb0b = Mb[NSYS][rB]; bb1b = Mb[NSYS + 1][rB]; diB = 1.0 / Mb[rB][rB]; }
    double acc0a = 0.0, acc1a = 0.0, acc0b = 0.0, acc1b = 0.0;
    double sol0a = 0.0, sol1a = 0.0, sol0b = 0.0, sol1b = 0.0;
#pragma unroll 1
    for (int p = NSYS - 1; p >= 0; --p) {
      const double tA0 = (bb0a - acc0a) * diA;
      const double tA1 = (bb1a - acc1a) * diA;
      const double tB0 = (bb0b - acc0b) * diB;
      const double tB1 = (bb1b - acc1b) * diB;
      const bool fromB = (p >= 64);
      const int  src   = fromB ? (p - 64) : p;
      const double x0 = rl_f64(fromB ? tB0 : tA0, src);
      const double x1 = rl_f64(fromB ? tB1 : tA1, src);
      if (p >= 64) { if (lane == p - 64) { sol0b = tB0; sol1b = tB1; } }
      else         { if (lane == p)      { sol0a = tA0; sol1a = tA1; } }
      if (rA < p) {
        const double u2 = Mb[p][rA];
        acc0a = fma(u2, x0, acc0a);
        acc1a = fma(u2, x1, acc1a);
      }
      if (hB && rB < p) {
        const double u2 = Mb[p][rB];
        acc0b = fma(u2, x0, acc0b);
        acc1b = fma(u2, x1, acc1b);
      }
    }
    ws[WS_WV + (size_t)b * 142 + 2 * rA]     = (float)sol0a;
    ws[WS_WV + (size_t)b * 142 + 2 * rA + 1] = (float)sol1a;
    if (hB) {
      ws[WS_WV + (size_t)b * 142 + 2 * rB]     = (float)sol0b;
      ws[WS_WV + (size_t)b * 142 + 2 * rB + 1] = (float)sol1b;
    }
  }
}

// ------------------------------- K3: fused spline eval + bilinear warp (+norm finalize)
__global__ __launch_bounds__(256) void k3_warp(const float* __restrict__ img,
                                               const float* __restrict__ ws,
                                               float* __restrict__ out) {
  const int orig = blockIdx.x;
  const int wgid = (orig & 7) * 256 + (orig >> 3);   // bijective (2048 % 8 == 0)
  const int b = wgid >> 8, y = wgid & 255;
  const int tid = threadIdx.x;   // = x

  if (orig == 0 && tid == 0) {
    float s = 0.f;
    for (int i = 0; i < NB; ++i) s += sqrtf(ws[WS_NORM + i]);
    out[OUT_NORM] = s * 0.125f;
  }

  __shared__ float s_c[NP], s_w[NP], s_v[6];
  if (tid < NP) {
    s_c[tid] = ws[WS_DST + b * NP + tid];
    s_w[tid] = ws[WS_WV + (size_t)b * 142 + tid];
  }
  if (tid >= NP && tid < NP + 6) s_v[tid - NP] = ws[WS_WV + (size_t)b * 142 + tid];
  __syncthreads();

  const float yf = (float)y, xf = (float)tid;
  float fy = fmaf(s_v[0], yf, fmaf(s_v[2], xf, s_v[4]));
  float fx = fmaf(s_v[1], yf, fmaf(s_v[3], xf, s_v[5]));
#pragma unroll 4
  for (int l = 0; l < NL; ++l) {
    const float dy = yf - s_c[2 * l];
    const float dx = xf - s_c[2 * l + 1];
    const float r  = fmaf(dy, dy, dx * dx);
    const float ph = 0.5f * r * __logf(fmaxf(r, 1e-10f));
    fy = fmaf(s_w[2 * l],     ph, fy);
    fx = fmaf(s_w[2 * l + 1], ph, fx);
  }

  const float qy = fminf(fmaxf(yf - fy, 0.f), 255.f);
  const float qx = fminf(fmaxf(xf - fx, 0.f), 255.f);
  int y0 = (int)floorf(qy); y0 = y0 > 254 ? 254 : y0;
  int x0 = (int)floorf(qx); x0 = x0 > 254 ? 254 : x0;
  const float wy = qy - (float)y0, wx = qx - (float)x0;
  const float w00 = (1.f - wy) * (1.f - wx), w01 = (1.f - wy) * wx;
  const float w10 = wy * (1.f - wx),         w11 = wy * wx;

  const float* p0 = img + (size_t)b * CIMG * 65536 + y0 * 256 + x0;
  const size_t ob = (size_t)b * CIMG * 65536 + (size_t)y * 256 + tid;
#pragma unroll 4
  for (int c = 0; c < CIMG; ++c) {
    const float* p = p0 + (size_t)c * 65536;
    const float v00 = p[0], v01 = p[1], v10 = p[256], v11 = p[257];
    const float val = fmaf(w00, v00, fmaf(w01, v01, fmaf(w10, v10, w11 * v11)));
    __builtin_nontemporal_store(val, &out[ob + (size_t)c * 65536]);
  }
}

// ------------------------------------------------------------------ launcher
extern "C" void kernel_launch(void* const* d_in, const int* in_sizes, int n_in,
                              void* d_out, int out_size, void* d_ws, size_t ws_size,
                              hipStream_t stream) {
  const float* x      = (const float*)d_in[0];
  const float* img    = (const float*)d_in[1];
  const float* scales = (const float*)d_in[2];
  const float* lmean  = (const float*)d_in[3];
  const float* W1     = (const float*)d_in[4];
  const float* b1     = (const float*)d_in[5];
  const float* W2     = (const float*)d_in[6];
  const float* b2     = (const float*)d_in[7];
  const float* W3     = (const float*)d_in[8];
  const float* b3     = (const float*)d_in[9];
  float* out = (float*)d_out;
  float* ws  = (float*)d_ws;

  k1_gemv<<<dim3(32, 32), 256, 0, stream>>>(x, W1, ws + WS_PART);
  k2_land_solve<<<NB, 256, 0, stream>>>(ws + WS_PART, scales, lmean, b1, W2, b2, W3, b3, out, ws);
  k3_warp<<<NB * HH, 256, 0, stream>>>(img, ws, out);
}